// Round 1
// baseline (1265.063 us; speedup 1.0000x reference)
//
#include <hip/hip_runtime.h>
#include <math.h>

#define Bsz 8
#define Lsz 8192
#define D 256
#define NROWS (Bsz*Lsz)      // 65536
#define NC 128               // chunks per sequence
#define CL (Lsz/NC)          // 64
#define TR 16                // rows per block in GEMV kernels
#define LN_EPS 1e-6f

__device__ __forceinline__ float gelu_tanh(float v){
    const float k0 = 0.7978845608028654f;   // sqrt(2/pi)
    const float k1 = 0.044715f;
    float inner = k0 * fmaf(k1*v*v, v, v);  // k0*(v + k1*v^3)
    return 0.5f * v * (1.0f + tanhf(inner));
}

// ---------------- K0: transpose 5 (256x256) matrices into ws ----------------
__global__ __launch_bounds__(256)
void k_transpose(const float* __restrict__ s0, const float* __restrict__ s1,
                 const float* __restrict__ s2, const float* __restrict__ s3,
                 const float* __restrict__ s4, float* __restrict__ dst){
    const float* s = (blockIdx.z==0)?s0:(blockIdx.z==1)?s1:(blockIdx.z==2)?s2:(blockIdx.z==3)?s3:s4;
    float* d = dst + (size_t)blockIdx.z * D * D;
    __shared__ float tile[32][33];
    int tx = threadIdx.x;            // 0..31
    int ty = threadIdx.y;            // 0..7
    int src_row0 = blockIdx.y*32;    // dest cols
    int src_col0 = blockIdx.x*32;    // dest rows
    #pragma unroll
    for (int i=0;i<4;i++){
        int a = ty*4+i;
        tile[a][tx] = s[(src_row0 + a)*D + src_col0 + tx];
    }
    __syncthreads();
    #pragma unroll
    for (int i=0;i<4;i++){
        int a = ty*4+i;              // dest row within tile
        d[(src_col0 + a)*D + src_row0 + tx] = tile[tx][a];
    }
}

// ---------------- K1: LayerNorm + Bu = gamma * (xn @ B^T) -------------------
__global__ __launch_bounds__(256)
void k_ln_bu(const float* __restrict__ x, const float* __restrict__ ln_scale,
             const float* __restrict__ ln_bias, const float* __restrict__ nu_log,
             const float* __restrict__ bt_re, const float* __restrict__ bt_im,
             float* __restrict__ bu_re, float* __restrict__ bu_im){
    __shared__ float xn[TR][D];
    int r0 = blockIdx.x * TR;
    int t  = threadIdx.x;
    int wave = t >> 6, lane = t & 63;

    // LayerNorm: each wave handles rows wave, wave+4, ...
    for (int rr = wave; rr < TR; rr += 4){
        const float* xr = x + (size_t)(r0 + rr) * D;
        float v[4]; float s = 0.f;
        #pragma unroll
        for (int i=0;i<4;i++){ v[i] = xr[lane + 64*i]; s += v[i]; }
        #pragma unroll
        for (int off=32; off; off>>=1) s += __shfl_xor(s, off);
        float mu = s * (1.0f/D);
        float vs = 0.f;
        #pragma unroll
        for (int i=0;i<4;i++){ float dd = v[i]-mu; vs += dd*dd; }
        #pragma unroll
        for (int off=32; off; off>>=1) vs += __shfl_xor(vs, off);
        float rstd = rsqrtf(vs*(1.0f/D) + LN_EPS);
        #pragma unroll
        for (int i=0;i<4;i++){
            int dd = lane + 64*i;
            xn[rr][dd] = (v[i]-mu)*rstd*ln_scale[dd] + ln_bias[dd];
        }
    }
    __syncthreads();

    float accre[TR], accim[TR];
    #pragma unroll
    for (int r=0;r<TR;r++){ accre[r]=0.f; accim[r]=0.f; }
    #pragma unroll 4
    for (int d=0; d<D; d++){
        float br = bt_re[d*D + t];
        float bi = bt_im[d*D + t];
        #pragma unroll
        for (int r=0;r<TR;r++){
            float xv = xn[r][d];
            accre[r] = fmaf(xv, br, accre[r]);
            accim[r] = fmaf(xv, bi, accim[r]);
        }
    }
    float gam = sqrtf(1.0f - expf(-2.0f*expf(nu_log[t])));
    #pragma unroll
    for (int r=0;r<TR;r++){
        bu_re[(size_t)(r0+r)*D + t] = accre[r]*gam;
        bu_im[(size_t)(r0+r)*D + t] = accim[r]*gam;
    }
}

// ---------------- K2: per-chunk local scan (zero init) ----------------------
__global__ __launch_bounds__(256)
void k_scan_local(const float* __restrict__ nu_log, const float* __restrict__ theta_log,
                  const float* __restrict__ bu_re, const float* __restrict__ bu_im,
                  float* __restrict__ e_re, float* __restrict__ e_im){
    int h = threadIdx.x;
    int bc = blockIdx.x;
    int b = bc / NC, c = bc % NC;
    float en = expf(nu_log[h]);
    float mag = expf(-en), th = expf(theta_log[h]);
    float lam_re = mag * cosf(th), lam_im = mag * sinf(th);
    const float* pr = bu_re + (size_t)(b*Lsz + c*CL)*D + h;
    const float* pi = bu_im + (size_t)(b*Lsz + c*CL)*D + h;
    float sr = 0.f, si = 0.f;
    #pragma unroll 4
    for (int tt=0; tt<CL; tt++){
        float ur = pr[(size_t)tt*D], ui = pi[(size_t)tt*D];
        float nsr = fmaf(lam_re, sr, fmaf(-lam_im, si, ur));
        float nsi = fmaf(lam_re, si, fmaf( lam_im, sr, ui));
        sr = nsr; si = nsi;
    }
    e_re[(c*Bsz + b)*D + h] = sr;
    e_im[(c*Bsz + b)*D + h] = si;
}

// ---------------- K3: combine chunk carries in fp64 -------------------------
__global__ __launch_bounds__(256)
void k_scan_combine(const float* __restrict__ nu_log, const float* __restrict__ theta_log,
                    const float* __restrict__ e_re, const float* __restrict__ e_im,
                    float* __restrict__ p_re, float* __restrict__ p_im){
    int h = threadIdx.x;
    int b = blockIdx.x;
    double en = exp((double)nu_log[h]);
    double th = exp((double)theta_log[h]);
    double mag = exp(-en);
    double lr = mag*cos(th), li = mag*sin(th);
    double ar = 1.0, ai = 0.0;               // lam^CL
    for (int i=0;i<CL;i++){
        double nr = ar*lr - ai*li;
        double ni = ar*li + ai*lr;
        ar = nr; ai = ni;
    }
    double sr = 0.0, si = 0.0;
    for (int c=0;c<NC;c++){
        int idx = (c*Bsz + b)*D + h;
        p_re[idx] = (float)sr; p_im[idx] = (float)si;
        double er = e_re[idx], ei = e_im[idx];
        double nr = ar*sr - ai*si + er;
        double ni = ar*si + ai*sr + ei;
        sr = nr; si = ni;
    }
}

// ---------------- K4: re-scan with carried prefix, in place -> h ------------
__global__ __launch_bounds__(256)
void k_scan_apply(const float* __restrict__ nu_log, const float* __restrict__ theta_log,
                  const float* __restrict__ p_re, const float* __restrict__ p_im,
                  float* __restrict__ bu_re, float* __restrict__ bu_im){
    int h = threadIdx.x;
    int bc = blockIdx.x;
    int b = bc / NC, c = bc % NC;
    float en = expf(nu_log[h]);
    float mag = expf(-en), th = expf(theta_log[h]);
    float lam_re = mag * cosf(th), lam_im = mag * sinf(th);
    int pidx = (c*Bsz + b)*D + h;
    float sr = p_re[pidx], si = p_im[pidx];
    float* pr = bu_re + (size_t)(b*Lsz + c*CL)*D + h;
    float* pi = bu_im + (size_t)(b*Lsz + c*CL)*D + h;
    #pragma unroll 4
    for (int tt=0; tt<CL; tt++){
        float ur = pr[(size_t)tt*D], ui = pi[(size_t)tt*D];
        float nsr = fmaf(lam_re, sr, fmaf(-lam_im, si, ur));
        float nsi = fmaf(lam_re, si, fmaf( lam_im, sr, ui));
        sr = nsr; si = nsi;
        pr[(size_t)tt*D] = sr; pi[(size_t)tt*D] = si;
    }
}

// ---------------- K5: y = Re(h C^T)+Dskip*xn; out = gelu(y) W^T + b + x -----
__global__ __launch_bounds__(256)
void k_out(const float* __restrict__ x, const float* __restrict__ ln_scale,
           const float* __restrict__ ln_bias,
           const float* __restrict__ h_re, const float* __restrict__ h_im,
           const float* __restrict__ ct_re, const float* __restrict__ ct_im,
           const float* __restrict__ d_skip, const float* __restrict__ wt,
           const float* __restrict__ bvec, float* __restrict__ out){
    __shared__ float xn[TR][D];
    __shared__ float hre[TR][D];
    __shared__ float him[TR][D];
    int r0 = blockIdx.x * TR;
    int t  = threadIdx.x;
    int wave = t >> 6, lane = t & 63;

    // LayerNorm (recompute)
    for (int rr = wave; rr < TR; rr += 4){
        const float* xr = x + (size_t)(r0 + rr) * D;
        float v[4]; float s = 0.f;
        #pragma unroll
        for (int i=0;i<4;i++){ v[i] = xr[lane + 64*i]; s += v[i]; }
        #pragma unroll
        for (int off=32; off; off>>=1) s += __shfl_xor(s, off);
        float mu = s * (1.0f/D);
        float vs = 0.f;
        #pragma unroll
        for (int i=0;i<4;i++){ float dd = v[i]-mu; vs += dd*dd; }
        #pragma unroll
        for (int off=32; off; off>>=1) vs += __shfl_xor(vs, off);
        float rstd = rsqrtf(vs*(1.0f/D) + LN_EPS);
        #pragma unroll
        for (int i=0;i<4;i++){
            int dd = lane + 64*i;
            xn[rr][dd] = (v[i]-mu)*rstd*ln_scale[dd] + ln_bias[dd];
        }
    }
    // load h rows
    #pragma unroll
    for (int r=0;r<TR;r++){
        hre[r][t] = h_re[(size_t)(r0+r)*D + t];
        him[r][t] = h_im[(size_t)(r0+r)*D + t];
    }
    __syncthreads();

    float acc[TR];
    #pragma unroll
    for (int r=0;r<TR;r++) acc[r]=0.f;
    #pragma unroll 4
    for (int hh=0; hh<D; hh++){
        float cr = ct_re[hh*D + t];
        float ci = ct_im[hh*D + t];
        #pragma unroll
        for (int r=0;r<TR;r++)
            acc[r] = fmaf(hre[r][hh], cr, fmaf(-him[r][hh], ci, acc[r]));
    }
    float ds = d_skip[t];
    float g[TR];
    #pragma unroll
    for (int r=0;r<TR;r++){
        float y = acc[r] + ds*xn[r][t];
        g[r] = gelu_tanh(y);
    }
    __syncthreads();                   // everyone done reading hre
    #pragma unroll
    for (int r=0;r<TR;r++) hre[r][t] = g[r];
    __syncthreads();

    float acc2[TR];
    #pragma unroll
    for (int r=0;r<TR;r++) acc2[r]=0.f;
    #pragma unroll 4
    for (int o=0; o<D; o++){
        float w = wt[o*D + t];
        #pragma unroll
        for (int r=0;r<TR;r++) acc2[r] = fmaf(hre[r][o], w, acc2[r]);
    }
    float bb = bvec[t];
    #pragma unroll
    for (int r=0;r<TR;r++){
        size_t idx = (size_t)(r0+r)*D + t;
        out[idx] = acc2[r] + bb + x[idx];
    }
}

extern "C" void kernel_launch(void* const* d_in, const int* in_sizes, int n_in,
                              void* d_out, int out_size, void* d_ws, size_t ws_size,
                              hipStream_t stream){
    const float* x         = (const float*)d_in[0];
    const float* ln_scale  = (const float*)d_in[1];
    const float* ln_bias   = (const float*)d_in[2];
    const float* nu_log    = (const float*)d_in[3];
    const float* theta_log = (const float*)d_in[4];
    const float* B_re      = (const float*)d_in[5];
    const float* B_im      = (const float*)d_in[6];
    const float* C_re      = (const float*)d_in[7];
    const float* C_im      = (const float*)d_in[8];
    const float* D_skip    = (const float*)d_in[9];
    const float* W         = (const float*)d_in[10];
    const float* bvec      = (const float*)d_in[11];
    float* out = (float*)d_out;

    float* ws = (float*)d_ws;
    size_t plane = (size_t)NROWS * D;          // 16,777,216 floats
    float* bu_re = ws;
    float* bu_im = bu_re + plane;
    float* e_re  = bu_im + plane;              // NC*Bsz*D = 262144
    float* e_im  = e_re + (size_t)NC*Bsz*D;
    float* p_re  = e_im + (size_t)NC*Bsz*D;
    float* p_im  = p_re + (size_t)NC*Bsz*D;
    float* tmats = p_im + (size_t)NC*Bsz*D;    // 5 * D*D
    float* bt_re = tmats + 0*(size_t)D*D;
    float* bt_im = tmats + 1*(size_t)D*D;
    float* ct_re = tmats + 2*(size_t)D*D;
    float* ct_im = tmats + 3*(size_t)D*D;
    float* wt    = tmats + 4*(size_t)D*D;

    k_transpose<<<dim3(8,8,5), dim3(32,8), 0, stream>>>(B_re, B_im, C_re, C_im, W, tmats);
    k_ln_bu<<<NROWS/TR, 256, 0, stream>>>(x, ln_scale, ln_bias, nu_log, bt_re, bt_im, bu_re, bu_im);
    k_scan_local<<<Bsz*NC, 256, 0, stream>>>(nu_log, theta_log, bu_re, bu_im, e_re, e_im);
    k_scan_combine<<<Bsz, 256, 0, stream>>>(nu_log, theta_log, e_re, e_im, p_re, p_im);
    k_scan_apply<<<Bsz*NC, 256, 0, stream>>>(nu_log, theta_log, p_re, p_im, bu_re, bu_im);
    k_out<<<NROWS/TR, 256, 0, stream>>>(x, ln_scale, ln_bias, bu_re, bu_im,
                                        ct_re, ct_im, D_skip, wt, bvec, out);
}

// Round 2
// 489.372 us; speedup vs baseline: 2.5851x; 2.5851x over previous
//
#include <hip/hip_runtime.h>
#include <math.h>
#include <stdint.h>

#define Bsz 8
#define Lsz 8192
#define D 256
#define NROWS (Bsz*Lsz)      // 65536
#define NC 128               // chunks per sequence
#define CL (Lsz/NC)          // 64
#define LN_EPS 1e-6f

typedef float f32x4 __attribute__((ext_vector_type(4)));
typedef short bf16x8 __attribute__((ext_vector_type(8)));
typedef short short4v __attribute__((ext_vector_type(4)));

__device__ __forceinline__ float gelu_tanh(float v){
    const float k0 = 0.7978845608028654f;   // sqrt(2/pi)
    const float k1 = 0.044715f;
    float inner = k0 * fmaf(k1*v*v, v, v);
    return 0.5f * v * (1.0f + tanhf(inner));
}

__device__ __forceinline__ uint16_t bf16_rne(float f){
    uint32_t u = __float_as_uint(f);
    return (uint16_t)((u + 0x7fffu + ((u>>16)&1u)) >> 16);
}
__device__ __forceinline__ float bf16_to_f(uint16_t h){
    return __uint_as_float(((uint32_t)h)<<16);
}
// pack (hi, lo) split of f into one dword: low16 = hi, high16 = lo
__device__ __forceinline__ uint32_t pack_split(float f){
    uint16_t hi = bf16_rne(f);
    uint16_t lo = bf16_rne(f - bf16_to_f(hi));
    return (uint32_t)hi | ((uint32_t)lo << 16);
}

// ------------- prep: split weight matrices into bf16 hi/lo planes ----------
// b1hat [512][256]: row n (<256 -> B_re, else B_im), col d ; value *= ln_scale[d]
// b2hat [256][512]: row n, col k (<256 -> C_re[n][k], else -C_im[n][k-256])
// b3hat [256][256]: W
__global__ __launch_bounds__(256)
void k_prep(const float* __restrict__ B_re, const float* __restrict__ B_im,
            const float* __restrict__ C_re, const float* __restrict__ C_im,
            const float* __restrict__ W, const float* __restrict__ ln_scale,
            short* __restrict__ b1_hi, short* __restrict__ b1_lo,
            short* __restrict__ b2_hi, short* __restrict__ b2_lo,
            short* __restrict__ b3_hi, short* __restrict__ b3_lo){
    int i = blockIdx.x*256 + threadIdx.x;   // up to 131072
    {   // b1
        int n = i >> 8, d = i & 255;
        float v = (n < 256 ? B_re[n*256 + d] : B_im[(n-256)*256 + d]) * ln_scale[d];
        uint16_t hi = bf16_rne(v);
        b1_hi[i] = (short)hi;
        b1_lo[i] = (short)bf16_rne(v - bf16_to_f(hi));
    }
    {   // b2
        int n = i >> 9, k = i & 511;
        float v = (k < 256) ? C_re[n*256 + k] : -C_im[n*256 + (k-256)];
        uint16_t hi = bf16_rne(v);
        b2_hi[i] = (short)hi;
        b2_lo[i] = (short)bf16_rne(v - bf16_to_f(hi));
    }
    if (i < 256*256){   // b3
        float v = W[i];
        uint16_t hi = bf16_rne(v);
        b3_hi[i] = (short)hi;
        b3_lo[i] = (short)bf16_rne(v - bf16_to_f(hi));
    }
}

// t1[n] = sum_d ln_scale[d]*B1[n][d] ; t2[n] = sum_d ln_bias[d]*B1[n][d]
__global__ __launch_bounds__(256)
void k_prep_t(const float* __restrict__ B_re, const float* __restrict__ B_im,
              const float* __restrict__ ln_scale, const float* __restrict__ ln_bias,
              float* __restrict__ t1, float* __restrict__ t2){
    int n = blockIdx.x*256 + threadIdx.x;
    if (n >= 512) return;
    const float* src = (n < 256) ? &B_re[n*256] : &B_im[(n-256)*256];
    float s1 = 0.f, s2 = 0.f;
    for (int d = 0; d < 256; d++){
        float b = src[d];
        s1 = fmaf(ln_scale[d], b, s1);
        s2 = fmaf(ln_bias[d],  b, s2);
    }
    t1[n] = s1; t2[n] = s2;
}

// ------------- per-row LayerNorm stats (mu, rstd) ---------------------------
__global__ __launch_bounds__(256)
void k_stats(const float* __restrict__ x, float* __restrict__ mu_arr,
             float* __restrict__ rstd_arr){
    int r0 = blockIdx.x * 16;
    int t = threadIdx.x;
    int wave = t >> 6, lane = t & 63;
    for (int rr = wave; rr < 16; rr += 4){
        const float* xr = x + (size_t)(r0 + rr) * D;
        float v[4]; float s = 0.f;
        #pragma unroll
        for (int i=0;i<4;i++){ v[i] = xr[lane + 64*i]; s += v[i]; }
        #pragma unroll
        for (int off=32; off; off>>=1) s += __shfl_xor(s, off);
        float mu = s * (1.0f/D);
        float vs = 0.f;
        #pragma unroll
        for (int i=0;i<4;i++){ float dd = v[i]-mu; vs += dd*dd; }
        #pragma unroll
        for (int off=32; off; off>>=1) vs += __shfl_xor(vs, off);
        float rstd = rsqrtf(vs*(1.0f/D) + LN_EPS);
        if (lane == 0){ mu_arr[r0+rr] = mu; rstd_arr[r0+rr] = rstd; }
    }
}

// ------------- unified MFMA GEMM (split-bf16, 3 products) -------------------
// block = 64 rows x 256 cols; 4 waves side-by-side in n (wave tile 64x64).
// MODE 1: A = x (fp32, split on the fly), K=256, N=512 (gridDim.y=2),
//         out fp32 bu planes with LN folded + gamma scale.
// MODE 2: A = [hre||him] packed hi/lo dwords, K=512, epilogue y+Dskip*xn ->
//         gelu -> packed g into gdst (aliases bu_re; disjoint 64-row stripes).
// MODE 3: A = packed g, K=256, epilogue +b +x -> d_out.
template<int MODE>
__global__ __launch_bounds__(256)
void k_gemm(const float* __restrict__ xsrc,
            const uint32_t* __restrict__ apk_re, const uint32_t* __restrict__ apk_im,
            const short* __restrict__ bhat_hi, const short* __restrict__ bhat_lo,
            const float* __restrict__ mu_arr, const float* __restrict__ rstd_arr,
            const float* __restrict__ t1, const float* __restrict__ t2,
            const float* __restrict__ nu_log,
            const float* __restrict__ ln_scale, const float* __restrict__ ln_bias,
            const float* __restrict__ d_skip, const float* __restrict__ bvec,
            float* __restrict__ out_re, float* __restrict__ out_im,
            uint32_t* __restrict__ gdst){
    constexpr int K = (MODE==2) ? 512 : 256;
    __shared__ __align__(16) short Ahi[64*40];
    __shared__ __align__(16) short Alo[64*40];
    const int t = threadIdx.x;
    const int wc = t >> 6;           // wave id = n-block 0..3
    const int lane = t & 63;
    const int lgrp = lane >> 4;      // k-group 0..3
    const int lrow = lane & 15;
    const int r0 = blockIdx.x * 64;
    const int cb = blockIdx.y * 256; // MODE1: 0 or 256

    f32x4 acc[4][4];
    #pragma unroll
    for (int mf=0;mf<4;mf++)
    #pragma unroll
    for (int nf=0;nf<4;nf++) acc[mf][nf] = (f32x4){0.f,0.f,0.f,0.f};

    const int srow = t >> 3;   // 0..31
    const int skq  = t & 7;    // k chunk of 4

    for (int k0 = 0; k0 < K; k0 += 32){
        __syncthreads();
        #pragma unroll
        for (int p=0; p<2; p++){
            int row = srow + p*32;
            int kk  = k0 + skq*4;
            short4v hiv, lov;
            if (MODE == 1){
                float4 xv = *(const float4*)&xsrc[(size_t)(r0+row)*256 + kk];
                float f[4] = {xv.x, xv.y, xv.z, xv.w};
                #pragma unroll
                for (int i=0;i<4;i++){
                    uint16_t hb = bf16_rne(f[i]);
                    hiv[i] = (short)hb;
                    lov[i] = (short)bf16_rne(f[i] - bf16_to_f(hb));
                }
            } else {
                const uint32_t* src = (MODE==2 && k0 >= 256) ? apk_im : apk_re;
                int col = (MODE==2 && k0 >= 256) ? (kk - 256) : kk;
                uint4 w = *(const uint4*)&src[(size_t)(r0+row)*256 + col];
                uint32_t ws[4] = {w.x, w.y, w.z, w.w};
                #pragma unroll
                for (int i=0;i<4;i++){
                    hiv[i] = (short)(ws[i] & 0xffffu);
                    lov[i] = (short)(ws[i] >> 16);
                }
            }
            *(short4v*)&Ahi[row*40 + skq*4] = hiv;
            *(short4v*)&Alo[row*40 + skq*4] = lov;
        }
        __syncthreads();

        bf16x8 ah[4], al[4], bh[4], bl[4];
        #pragma unroll
        for (int mf=0;mf<4;mf++){
            ah[mf] = *(const bf16x8*)&Ahi[(mf*16+lrow)*40 + lgrp*8];
            al[mf] = *(const bf16x8*)&Alo[(mf*16+lrow)*40 + lgrp*8];
        }
        #pragma unroll
        for (int nf=0;nf<4;nf++){
            size_t boff = (size_t)(cb + wc*64 + nf*16 + lrow)*K + k0 + lgrp*8;
            bh[nf] = *(const bf16x8*)&bhat_hi[boff];
            bl[nf] = *(const bf16x8*)&bhat_lo[boff];
        }
        #pragma unroll
        for (int mf=0;mf<4;mf++)
        #pragma unroll
        for (int nf=0;nf<4;nf++){
            acc[mf][nf] = __builtin_amdgcn_mfma_f32_16x16x32_bf16(ah[mf], bh[nf], acc[mf][nf], 0,0,0);
            acc[mf][nf] = __builtin_amdgcn_mfma_f32_16x16x32_bf16(ah[mf], bl[nf], acc[mf][nf], 0,0,0);
            acc[mf][nf] = __builtin_amdgcn_mfma_f32_16x16x32_bf16(al[mf], bh[nf], acc[mf][nf], 0,0,0);
        }
    }

    // ---- epilogue ----
    #pragma unroll
    for (int nf=0; nf<4; nf++){
        const int lcol = wc*64 + nf*16 + lrow;   // local col 0..255
        if (MODE == 1){
            float gam = sqrtf(1.0f - expf(-2.0f*expf(nu_log[lcol])));
            float t1v = t1[cb + lcol], t2v = t2[cb + lcol];
            float* dst = (cb == 0) ? out_re : out_im;
            #pragma unroll
            for (int mf=0;mf<4;mf++){
                #pragma unroll
                for (int j=0;j<4;j++){
                    int row = mf*16 + lgrp*4 + j;
                    float rs = rstd_arr[r0+row], muv = mu_arr[r0+row];
                    float val = gam * (rs*acc[mf][nf][j] - rs*muv*t1v + t2v);
                    dst[(size_t)(r0+row)*256 + lcol] = val;
                }
            }
        } else if (MODE == 2){
            float dsk = d_skip[lcol], sc = ln_scale[lcol], bi = ln_bias[lcol];
            #pragma unroll
            for (int mf=0;mf<4;mf++){
                #pragma unroll
                for (int j=0;j<4;j++){
                    int row = mf*16 + lgrp*4 + j;
                    size_t idx = (size_t)(r0+row)*256 + lcol;
                    float rs = rstd_arr[r0+row], muv = mu_arr[r0+row];
                    float xn = (xsrc[idx] - muv)*rs*sc + bi;
                    float y  = acc[mf][nf][j] + dsk*xn;
                    gdst[idx] = pack_split(gelu_tanh(y));
                }
            }
        } else {
            float bb = bvec[lcol];
            #pragma unroll
            for (int mf=0;mf<4;mf++){
                #pragma unroll
                for (int j=0;j<4;j++){
                    int row = mf*16 + lgrp*4 + j;
                    size_t idx = (size_t)(r0+row)*256 + lcol;
                    out_re[idx] = acc[mf][nf][j] + bb + xsrc[idx];
                }
            }
        }
    }
}

// ---------------- scan kernels (fp32 bu -> packed h in place) ---------------
__global__ __launch_bounds__(256)
void k_scan_local(const float* __restrict__ nu_log, const float* __restrict__ theta_log,
                  const float* __restrict__ bu_re, const float* __restrict__ bu_im,
                  float* __restrict__ e_re, float* __restrict__ e_im){
    int h = threadIdx.x;
    int bc = blockIdx.x;
    int b = bc / NC, c = bc % NC;
    float en = expf(nu_log[h]);
    float mag = expf(-en), th = expf(theta_log[h]);
    float lam_re = mag * cosf(th), lam_im = mag * sinf(th);
    const float* pr = bu_re + (size_t)(b*Lsz + c*CL)*D + h;
    const float* pi = bu_im + (size_t)(b*Lsz + c*CL)*D + h;
    float sr = 0.f, si = 0.f;
    #pragma unroll 4
    for (int tt=0; tt<CL; tt++){
        float ur = pr[(size_t)tt*D], ui = pi[(size_t)tt*D];
        float nsr = fmaf(lam_re, sr, fmaf(-lam_im, si, ur));
        float nsi = fmaf(lam_re, si, fmaf( lam_im, sr, ui));
        sr = nsr; si = nsi;
    }
    e_re[(c*Bsz + b)*D + h] = sr;
    e_im[(c*Bsz + b)*D + h] = si;
}

__global__ __launch_bounds__(256)
void k_scan_combine(const float* __restrict__ nu_log, const float* __restrict__ theta_log,
                    const float* __restrict__ e_re, const float* __restrict__ e_im,
                    float* __restrict__ p_re, float* __restrict__ p_im){
    int h = threadIdx.x;
    int b = blockIdx.x;
    double en = exp((double)nu_log[h]);
    double th = exp((double)theta_log[h]);
    double mag = exp(-en);
    double lr = mag*cos(th), li = mag*sin(th);
    double ar = 1.0, ai = 0.0;               // lam^CL
    for (int i=0;i<CL;i++){
        double nr = ar*lr - ai*li;
        double ni = ar*li + ai*lr;
        ar = nr; ai = ni;
    }
    double sr = 0.0, si = 0.0;
    for (int c=0;c<NC;c++){
        int idx = (c*Bsz + b)*D + h;
        p_re[idx] = (float)sr; p_im[idx] = (float)si;
        double er = e_re[idx], ei = e_im[idx];
        double nr = ar*sr - ai*si + er;
        double ni = ar*si + ai*sr + ei;
        sr = nr; si = ni;
    }
}

__global__ __launch_bounds__(256)
void k_scan_apply(const float* __restrict__ nu_log, const float* __restrict__ theta_log,
                  const float* __restrict__ p_re, const float* __restrict__ p_im,
                  float* __restrict__ bu_re, float* __restrict__ bu_im){
    int h = threadIdx.x;
    int bc = blockIdx.x;
    int b = bc / NC, c = bc % NC;
    float en = expf(nu_log[h]);
    float mag = expf(-en), th = expf(theta_log[h]);
    float lam_re = mag * cosf(th), lam_im = mag * sinf(th);
    int pidx = (c*Bsz + b)*D + h;
    float sr = p_re[pidx], si = p_im[pidx];
    float* pr = bu_re + (size_t)(b*Lsz + c*CL)*D + h;
    float* pi = bu_im + (size_t)(b*Lsz + c*CL)*D + h;
    #pragma unroll 4
    for (int tt=0; tt<CL; tt++){
        float ur = pr[(size_t)tt*D], ui = pi[(size_t)tt*D];
        float nsr = fmaf(lam_re, sr, fmaf(-lam_im, si, ur));
        float nsi = fmaf(lam_re, si, fmaf( lam_im, sr, ui));
        sr = nsr; si = nsi;
        *(uint32_t*)&pr[(size_t)tt*D] = pack_split(sr);   // h packed hi/lo
        *(uint32_t*)&pi[(size_t)tt*D] = pack_split(si);
    }
}

extern "C" void kernel_launch(void* const* d_in, const int* in_sizes, int n_in,
                              void* d_out, int out_size, void* d_ws, size_t ws_size,
                              hipStream_t stream){
    const float* x         = (const float*)d_in[0];
    const float* ln_scale  = (const float*)d_in[1];
    const float* ln_bias   = (const float*)d_in[2];
    const float* nu_log    = (const float*)d_in[3];
    const float* theta_log = (const float*)d_in[4];
    const float* B_re      = (const float*)d_in[5];
    const float* B_im      = (const float*)d_in[6];
    const float* C_re      = (const float*)d_in[7];
    const float* C_im      = (const float*)d_in[8];
    const float* D_skip    = (const float*)d_in[9];
    const float* W         = (const float*)d_in[10];
    const float* bvec      = (const float*)d_in[11];
    float* out = (float*)d_out;

    char* base = (char*)d_ws;
    size_t off = 0;
    auto alloc = [&](size_t bytes)->char*{
        char* p = base + off;
        off += (bytes + 255) & ~(size_t)255;
        return p;
    };
    float*  bu_re = (float*)alloc((size_t)NROWS*D*4);
    float*  bu_im = (float*)alloc((size_t)NROWS*D*4);
    float*  mu_a  = (float*)alloc((size_t)NROWS*4);
    float*  rs_a  = (float*)alloc((size_t)NROWS*4);
    float*  e_re  = (float*)alloc((size_t)NC*Bsz*D*4);
    float*  e_im  = (float*)alloc((size_t)NC*Bsz*D*4);
    float*  p_re  = (float*)alloc((size_t)NC*Bsz*D*4);
    float*  p_im  = (float*)alloc((size_t)NC*Bsz*D*4);
    float*  t1    = (float*)alloc(512*4);
    float*  t2    = (float*)alloc(512*4);
    short*  b1_hi = (short*)alloc(512*256*2);
    short*  b1_lo = (short*)alloc(512*256*2);
    short*  b2_hi = (short*)alloc(256*512*2);
    short*  b2_lo = (short*)alloc(256*512*2);
    short*  b3_hi = (short*)alloc(256*256*2);
    short*  b3_lo = (short*)alloc(256*256*2);

    k_prep<<<512, 256, 0, stream>>>(B_re, B_im, C_re, C_im, W, ln_scale,
                                    b1_hi, b1_lo, b2_hi, b2_lo, b3_hi, b3_lo);
    k_prep_t<<<2, 256, 0, stream>>>(B_re, B_im, ln_scale, ln_bias, t1, t2);
    k_stats<<<NROWS/16, 256, 0, stream>>>(x, mu_a, rs_a);

    // GEMM1: Bu (re|im packed as N=512)
    k_gemm<1><<<dim3(NROWS/64, 2), 256, 0, stream>>>(
        x, nullptr, nullptr, b1_hi, b1_lo, mu_a, rs_a, t1, t2, nu_log,
        ln_scale, ln_bias, D_skip, bvec, bu_re, bu_im, nullptr);

    k_scan_local<<<Bsz*NC, 256, 0, stream>>>(nu_log, theta_log, bu_re, bu_im, e_re, e_im);
    k_scan_combine<<<Bsz, 256, 0, stream>>>(nu_log, theta_log, e_re, e_im, p_re, p_im);
    k_scan_apply<<<Bsz*NC, 256, 0, stream>>>(nu_log, theta_log, p_re, p_im, bu_re, bu_im);

    // GEMM2: y = Re(h C^T) + Dskip*xn -> gelu -> packed g (aliases bu_re)
    k_gemm<2><<<dim3(NROWS/64, 1), 256, 0, stream>>>(
        x, (const uint32_t*)bu_re, (const uint32_t*)bu_im, b2_hi, b2_lo,
        mu_a, rs_a, t1, t2, nu_log, ln_scale, ln_bias, D_skip, bvec,
        nullptr, nullptr, (uint32_t*)bu_re);

    // GEMM3: out = g W^T + b + x
    k_gemm<3><<<dim3(NROWS/64, 1), 256, 0, stream>>>(
        x, (const uint32_t*)bu_re, nullptr, b3_hi, b3_lo,
        mu_a, rs_a, t1, t2, nu_log, ln_scale, ln_bias, D_skip, bvec,
        out, nullptr, nullptr);
}